// Round 2
// baseline (436.274 us; speedup 1.0000x reference)
//
#include <hip/hip_runtime.h>

// y[m, p*32+q] = (W2 · X_m · W1^T)[p,q] + bias[p*32+q],  X_m = reshape(x[m], 32, 32)
//
// One wave per row m. All global traffic is contiguous 1KB/instr:
//   4x load_dwordx4 -> LDS (XOR-swizzled) -> A-frag reads (b128)
//   stage1 MFMA -> T LDS round-trip -> stage2 MFMA
//   Y: 16x ds_write_b32 (pad-36 row stride, 2-way free) -> 4x ds_read_b128
//      -> +bias (preloaded row-major) -> 4x store_dwordx4
// All LDS use is intra-wave (disjoint per-wave regions): no __syncthreads.

typedef short bf16x8 __attribute__((ext_vector_type(8)));   // 8 bf16 = 4 VGPRs
typedef float f32x16 __attribute__((ext_vector_type(16)));  // C/D acc

#define MFMA32(A, B, C) __builtin_amdgcn_mfma_f32_32x32x16_bf16((A), (B), (C), 0, 0, 0)

// fp32 -> bf16, round-to-nearest-even
__device__ __forceinline__ short f2bf(float f) {
    unsigned u = __builtin_bit_cast(unsigned, f);
    u = (u + 0x7fffu + ((u >> 16) & 1u)) >> 16;
    return (short)u;
}

constexpr int M_TOTAL = 8 * 8192;            // 65536 rows of 1024
constexpr int BLOCKS  = 2048;
constexpr int TPB     = 256;                 // 4 waves/block
constexpr int NWAVES  = BLOCKS * (TPB / 64); // 8192 waves -> 8 rows/wave

// per-wave LDS: xy buffer (X: 1024 floats / Y: 32 rows x 36 padded) + T buffer
constexpr int XY_F = 1152;                   // max(1024, 32*36)
constexpr int T_F  = 1024;                   // 32 cols x 8 chunks x 4
constexpr int PW_F = XY_F + T_F;             // 2176 floats = 8704 B / wave

__global__ __launch_bounds__(TPB) void kron_mlp_kernel(
    const float* __restrict__ x,    // (65536, 1024)
    const float* __restrict__ w1,   // (32, 32): W1[q][s]
    const float* __restrict__ w2,   // (32, 32): W2[p][r]
    const float* __restrict__ bias, // (1024,)
    float* __restrict__ out)        // (65536, 1024)
{
    __shared__ float lds[4 * PW_F];  // 34816 B

    const int tid  = threadIdx.x;
    const int wid  = tid >> 6;
    const int lane = tid & 63;
    const int q    = lane & 31;   // C/D col; B col; A row
    const int h    = lane >> 5;   // half-wave k-range selector
    const int qx   = q & 7;       // XOR swizzle key

    float* xb = lds + wid * PW_F;        // X staging / Y staging
    float* tb = xb + XY_F;               // T round-trip

    // ---- loop-invariant fragments ----
    // B-frag of W1^T: element[k=8h+j][n=q] = W1[q][8h+j]
    bf16x8 w1b0, w1b1;
    {
        const float* p0 = w1 + q * 32 + 8 * h;
        #pragma unroll
        for (int j = 0; j < 8; ++j) { w1b0[j] = f2bf(p0[j]); w1b1[j] = f2bf(p0[16 + j]); }
    }
    // A-frag of W2: element[m=q(=p)][k=8h+j] = W2[q][8h+j]
    bf16x8 w2a0, w2a1;
    {
        const float* p0 = w2 + q * 32 + 8 * h;
        #pragma unroll
        for (int j = 0; j < 8; ++j) { w2a0[j] = f2bf(p0[j]); w2a1[j] = f2bf(p0[16 + j]); }
    }
    // bias in ROW-MAJOR store-frag layout: float4 #(j*64+lane) of bias[1024]
    float4 bias4[4];
    #pragma unroll
    for (int j = 0; j < 4; ++j)
        bias4[j] = *(const float4*)(bias + (j * 64 + lane) * 4);

    const int gwave = blockIdx.x * (TPB / 64) + wid;

    for (int m = gwave; m < M_TOTAL; m += NWAVES) {
        const float* xr = x + (size_t)m * 1024;

        // ---- coalesced load: 4 x 1KB contiguous ----
        float4 xv[4];
        #pragma unroll
        for (int j = 0; j < 4; ++j)
            xv[j] = *(const float4*)(xr + (j * 64 + lane) * 4);

        // ---- stage X into LDS, XOR-swizzled chunks ----
        // logical: row r = chunk/8, col-chunk c = chunk%8; phys c' = c ^ (r&7)
        #pragma unroll
        for (int j = 0; j < 4; ++j) {
            const int cl = j * 64 + lane;
            const int r  = cl >> 3, c = cl & 7;
            *(float4*)(xb + r * 32 + ((c ^ (r & 7)) << 2)) = xv[j];
        }

        // ---- read A-frags of X: lane (q,h) wants floats q*32 + {8h..8h+7, 16+8h..16+8h+7}
        const float4 ra0 = *(const float4*)(xb + q * 32 + (((2 * h + 0) ^ qx) << 2));
        const float4 ra1 = *(const float4*)(xb + q * 32 + (((2 * h + 1) ^ qx) << 2));
        const float4 ra2 = *(const float4*)(xb + q * 32 + (((4 + 2 * h) ^ qx) << 2));
        const float4 ra3 = *(const float4*)(xb + q * 32 + (((5 + 2 * h) ^ qx) << 2));

        bf16x8 a0, a1;
        a0[0] = f2bf(ra0.x); a0[1] = f2bf(ra0.y); a0[2] = f2bf(ra0.z); a0[3] = f2bf(ra0.w);
        a0[4] = f2bf(ra1.x); a0[5] = f2bf(ra1.y); a0[6] = f2bf(ra1.z); a0[7] = f2bf(ra1.w);
        a1[0] = f2bf(ra2.x); a1[1] = f2bf(ra2.y); a1[2] = f2bf(ra2.z); a1[3] = f2bf(ra2.w);
        a1[4] = f2bf(ra3.x); a1[5] = f2bf(ra3.y); a1[6] = f2bf(ra3.z); a1[7] = f2bf(ra3.w);

        // ---- Stage 1: T = X · W1^T ----
        f32x16 t = {};
        t = MFMA32(a0, w1b0, t);
        t = MFMA32(a1, w1b1, t);

        // ---- T round-trip: C/D -> B-operand layout ----
        #pragma unroll
        for (int g = 0; g < 4; ++g) {
            float4 v = { t[4 * g + 0], t[4 * g + 1], t[4 * g + 2], t[4 * g + 3] };
            *(float4*)(tb + (q * 8 + ((2 * g + h) ^ qx)) * 4) = v;
        }
        const float4 r0 = *(const float4*)(tb + (q * 8 + ((2 * h + 0) ^ qx)) * 4);
        const float4 r1 = *(const float4*)(tb + (q * 8 + ((2 * h + 1) ^ qx)) * 4);
        const float4 r2 = *(const float4*)(tb + (q * 8 + ((4 + 2 * h) ^ qx)) * 4);
        const float4 r3 = *(const float4*)(tb + (q * 8 + ((5 + 2 * h) ^ qx)) * 4);

        bf16x8 tb0, tb1;
        tb0[0] = f2bf(r0.x); tb0[1] = f2bf(r0.y); tb0[2] = f2bf(r0.z); tb0[3] = f2bf(r0.w);
        tb0[4] = f2bf(r1.x); tb0[5] = f2bf(r1.y); tb0[6] = f2bf(r1.z); tb0[7] = f2bf(r1.w);
        tb1[0] = f2bf(r2.x); tb1[1] = f2bf(r2.y); tb1[2] = f2bf(r2.z); tb1[3] = f2bf(r2.w);
        tb1[4] = f2bf(r3.x); tb1[5] = f2bf(r3.y); tb1[6] = f2bf(r3.z); tb1[7] = f2bf(r3.w);

        // ---- Stage 2: Y = W2 · T ----
        f32x16 y = {};
        y = MFMA32(w2a0, tb0, y);
        y = MFMA32(w2a1, tb1, y);

        // ---- Y staging: scattered dword writes (row stride 36: bank-safe),
        //      contiguous b128 reads in store order ----
        #pragma unroll
        for (int g = 0; g < 4; ++g)
            #pragma unroll
            for (int i = 0; i < 4; ++i)
                xb[(i + 8 * g + 4 * h) * 36 + q] = y[4 * g + i];

        float* orow = out + (size_t)m * 1024;
        #pragma unroll
        for (int j = 0; j < 4; ++j) {
            const int cl = j * 64 + lane;
            const int p  = cl >> 3, c = cl & 7;
            float4 v = *(const float4*)(xb + p * 36 + (c << 2));
            v.x += bias4[j].x; v.y += bias4[j].y; v.z += bias4[j].z; v.w += bias4[j].w;
            *(float4*)(orow + cl * 4) = v;
        }
    }
}

extern "C" void kernel_launch(void* const* d_in, const int* in_sizes, int n_in,
                              void* d_out, int out_size, void* d_ws, size_t ws_size,
                              hipStream_t stream) {
    const float* x    = (const float*)d_in[0];
    const float* w1   = (const float*)d_in[1];
    const float* w2   = (const float*)d_in[2];
    const float* bias = (const float*)d_in[3];
    float* out        = (float*)d_out;
    kron_mlp_kernel<<<dim3(BLOCKS), dim3(TPB), 0, stream>>>(x, w1, w2, bias, out);
}